// Round 3
// baseline (151.272 us; speedup 1.0000x reference)
//
#include <hip/hip_runtime.h>

// out[n, lm, c] = sum_{e: recv[e]==n} node_feats[send[e], c] * edge_attrs[e, lm]
//                 * tp_weights[e, L_MAP[lm], c]
// receiver_list sorted; first_occ[n] = segment start. No atomics.
// Lane layout (wave=64): h = lane>>5 (edge parity), j = lane&31 (channel group,
// channels 4j..4j+3 as float4). Each wave = one node, processes 2 edges/iter.
// Block = 128 threads = 2 waves = 2 nodes.

typedef float f32x4 __attribute__((ext_vector_type(4)));   // clang vector: OK for nontemporal builtins

__device__ __forceinline__ void fma4(f32x4& a, const f32x4 p, const float s) {
    a.x = fmaf(p.x, s, a.x); a.y = fmaf(p.y, s, a.y);
    a.z = fmaf(p.z, s, a.z); a.w = fmaf(p.w, s, a.w);
}

__global__ __launch_bounds__(128)
void impt_kernel(const float* __restrict__ node_feats,
                 const float* __restrict__ edge_attrs,
                 const float* __restrict__ tp_weights,
                 const int*   __restrict__ sender_list,
                 const int*   __restrict__ first_occ,
                 float*       __restrict__ out,
                 int nnodes, int nedges)
{
    const int tid  = threadIdx.x;
    const int wv   = tid >> 6;            // wave in block -> node offset
    const int lane = tid & 63;
    const int h    = lane >> 5;           // edge-parity half
    const int j    = lane & 31;           // channel group (4 channels)
    const int n    = blockIdx.x * 2 + wv;
    if (n >= nnodes) return;

    const int start = first_occ[n];
    const int end   = (n + 1 < nnodes) ? first_occ[n + 1] : nedges;

    f32x4 acc[16];
#pragma unroll
    for (int i = 0; i < 16; ++i) acc[i] = (f32x4)0.f;

    auto edge_body = [&](int ee) {
        const int s = sender_list[ee];
        const f32x4 sf = *reinterpret_cast<const f32x4*>(node_feats + (size_t)s * 128 + 4 * j);

        const f32x4* twp = reinterpret_cast<const f32x4*>(tp_weights + (size_t)ee * 512 + 4 * j);
        const f32x4 t0 = __builtin_nontemporal_load(twp);
        const f32x4 t1 = __builtin_nontemporal_load(twp + 32);   // +128 floats
        const f32x4 t2 = __builtin_nontemporal_load(twp + 64);
        const f32x4 t3 = __builtin_nontemporal_load(twp + 96);

        const f32x4* ea4 = reinterpret_cast<const f32x4*>(edge_attrs + (size_t)ee * 16);
        const f32x4 ea0 = __builtin_nontemporal_load(ea4);
        const f32x4 ea1 = __builtin_nontemporal_load(ea4 + 1);
        const f32x4 ea2 = __builtin_nontemporal_load(ea4 + 2);
        const f32x4 ea3 = __builtin_nontemporal_load(ea4 + 3);

        const f32x4 p0 = sf * t0;
        const f32x4 p1 = sf * t1;
        const f32x4 p2 = sf * t2;
        const f32x4 p3 = sf * t3;

        // L_MAP = [0, 1,1,1, 2,2,2,2,2, 3,3,3,3,3,3,3]
        fma4(acc[0],  p0, ea0.x);
        fma4(acc[1],  p1, ea0.y);
        fma4(acc[2],  p1, ea0.z);
        fma4(acc[3],  p1, ea0.w);
        fma4(acc[4],  p2, ea1.x);
        fma4(acc[5],  p2, ea1.y);
        fma4(acc[6],  p2, ea1.z);
        fma4(acc[7],  p2, ea1.w);
        fma4(acc[8],  p2, ea2.x);
        fma4(acc[9],  p3, ea2.y);
        fma4(acc[10], p3, ea2.z);
        fma4(acc[11], p3, ea2.w);
        fma4(acc[12], p3, ea3.x);
        fma4(acc[13], p3, ea3.y);
        fma4(acc[14], p3, ea3.z);
        fma4(acc[15], p3, ea3.w);
    };

    // branch-free main loop over edge pairs; lane-half h picks edge e+h
    const int cnt    = end - start;
    const int npairs = cnt >> 1;
    int e = start;
    for (int it = 0; it < npairs; ++it, e += 2) {
        edge_body(e + h);
    }
    if (cnt & 1) {              // odd tail: only half 0 takes the last edge
        if (h == 0) edge_body(end - 1);
    }

    // combine the two edge-parity halves (lane ^ 32)
#pragma unroll
    for (int i = 0; i < 16; ++i) {
        acc[i].x += __shfl_xor(acc[i].x, 32);
        acc[i].y += __shfl_xor(acc[i].y, 32);
        acc[i].z += __shfl_xor(acc[i].z, 32);
        acc[i].w += __shfl_xor(acc[i].w, 32);
    }

    // stores: half h writes lm = 2*i + h -> contiguous 1 KiB per i across the wave
    float* o = out + (size_t)n * 2048 + 4 * j;
#pragma unroll
    for (int i = 0; i < 8; ++i) {
        const f32x4 v = (h == 0) ? acc[2 * i] : acc[2 * i + 1];   // compile-time acc idx
        *reinterpret_cast<f32x4*>(o + (size_t)(2 * i + h) * 128) = v;
    }
}

extern "C" void kernel_launch(void* const* d_in, const int* in_sizes, int n_in,
                              void* d_out, int out_size, void* d_ws, size_t ws_size,
                              hipStream_t stream)
{
    const float* node_feats  = (const float*)d_in[0];
    const float* edge_attrs  = (const float*)d_in[1];
    const float* tp_weights  = (const float*)d_in[2];
    const int*   sender_list = (const int*)d_in[3];
    // d_in[4] = receiver_list (unused; first_occurences encodes the segments)
    const int*   first_occ   = (const int*)d_in[5];

    const int nnodes = in_sizes[5];          // 10000
    const int nedges = in_sizes[3];          // 160000

    const int nblocks = (nnodes + 1) / 2;    // 2 nodes (waves) per block
    impt_kernel<<<nblocks, 128, 0, stream>>>(node_feats, edge_attrs, tp_weights,
                                             sender_list, first_occ,
                                             (float*)d_out, nnodes, nedges);
}

// Round 4
// 129.445 us; speedup vs baseline: 1.1686x; 1.1686x over previous
//
#include <hip/hip_runtime.h>

// out[n, lm, c] = sum_{e: recv[e]==n} node_feats[send[e], c] * edge_attrs[e, lm]
//                 * tp_weights[e, L_MAP[lm], c]
// receiver_list sorted; first_occ[n] = segment start. No atomics.
// 1 wave = 1 node; lane = channel-pair (channels 2*lane, 2*lane+1) -> all row
// accesses are 512 B/wave single instructions. acc = f32x2[16] (32 VGPR).
// Next edge's sender index + node_feats row prefetched one iteration ahead.

typedef float f32x2 __attribute__((ext_vector_type(2)));
typedef float f32x4 __attribute__((ext_vector_type(4)));

__device__ __forceinline__ void fma2(f32x2& a, const f32x2 p, const float s) {
    a.x = fmaf(p.x, s, a.x);
    a.y = fmaf(p.y, s, a.y);
}

__global__ __launch_bounds__(256)
void impt_kernel(const float* __restrict__ node_feats,
                 const float* __restrict__ edge_attrs,
                 const float* __restrict__ tp_weights,
                 const int*   __restrict__ sender_list,
                 const int*   __restrict__ first_occ,
                 float*       __restrict__ out,
                 int nnodes, int nedges)
{
    const int tid  = threadIdx.x;
    const int wv   = tid >> 6;                  // wave in block
    const int lane = tid & 63;                  // channel-pair index
    const int n    = blockIdx.x * 4 + wv;       // 4 nodes per block (4 waves)
    if (n >= nnodes) return;

    const int start = first_occ[n];
    const int end   = (n + 1 < nnodes) ? first_occ[n + 1] : nedges;

    f32x2 acc[16];
#pragma unroll
    for (int i = 0; i < 16; ++i) acc[i] = (f32x2)0.f;

    const float* nf_base = node_feats + 2 * lane;
    const float* tw_base = tp_weights + 2 * lane;

    if (start < end) {
        // prefetch edge `start`
        int s0 = sender_list[start];
        f32x2 sf_next = *reinterpret_cast<const f32x2*>(nf_base + (size_t)s0 * 128);

        for (int e = start; e < end; ++e) {
            const f32x2 sf = sf_next;
            if (e + 1 < end) {                  // wave-uniform condition
                const int s = sender_list[e + 1];
                sf_next = *reinterpret_cast<const f32x2*>(nf_base + (size_t)s * 128);
            }

            const f32x2* twp = reinterpret_cast<const f32x2*>(tw_base + (size_t)e * 512);
            const f32x2 t0 = twp[0];            // each: 512 B / wave, coalesced
            const f32x2 t1 = twp[64];
            const f32x2 t2 = twp[128];
            const f32x2 t3 = twp[192];

            const f32x4* ea4 = reinterpret_cast<const f32x4*>(edge_attrs + (size_t)e * 16);
            const f32x4 ea0 = ea4[0];           // uniform-address broadcasts
            const f32x4 ea1 = ea4[1];
            const f32x4 ea2 = ea4[2];
            const f32x4 ea3 = ea4[3];

            const f32x2 p0 = sf * t0;
            const f32x2 p1 = sf * t1;
            const f32x2 p2 = sf * t2;
            const f32x2 p3 = sf * t3;

            // L_MAP = [0, 1,1,1, 2,2,2,2,2, 3,3,3,3,3,3,3]
            fma2(acc[0],  p0, ea0.x);
            fma2(acc[1],  p1, ea0.y);
            fma2(acc[2],  p1, ea0.z);
            fma2(acc[3],  p1, ea0.w);
            fma2(acc[4],  p2, ea1.x);
            fma2(acc[5],  p2, ea1.y);
            fma2(acc[6],  p2, ea1.z);
            fma2(acc[7],  p2, ea1.w);
            fma2(acc[8],  p2, ea2.x);
            fma2(acc[9],  p3, ea2.y);
            fma2(acc[10], p3, ea2.z);
            fma2(acc[11], p3, ea2.w);
            fma2(acc[12], p3, ea3.x);
            fma2(acc[13], p3, ea3.y);
            fma2(acc[14], p3, ea3.z);
            fma2(acc[15], p3, ea3.w);
        }
    }

    // 16 coalesced 512 B/wave stores (zeros if node has no edges)
    float* o = out + (size_t)n * 2048 + 2 * lane;
#pragma unroll
    for (int lm = 0; lm < 16; ++lm) {
        *reinterpret_cast<f32x2*>(o + (size_t)lm * 128) = acc[lm];
    }
}

extern "C" void kernel_launch(void* const* d_in, const int* in_sizes, int n_in,
                              void* d_out, int out_size, void* d_ws, size_t ws_size,
                              hipStream_t stream)
{
    const float* node_feats  = (const float*)d_in[0];
    const float* edge_attrs  = (const float*)d_in[1];
    const float* tp_weights  = (const float*)d_in[2];
    const int*   sender_list = (const int*)d_in[3];
    // d_in[4] = receiver_list (unused; first_occurences encodes the segments)
    const int*   first_occ   = (const int*)d_in[5];

    const int nnodes = in_sizes[5];          // 10000
    const int nedges = in_sizes[3];          // 160000

    const int nblocks = (nnodes + 3) / 4;    // 4 nodes (waves) per block
    impt_kernel<<<nblocks, 256, 0, stream>>>(node_feats, edge_attrs, tp_weights,
                                             sender_list, first_occ,
                                             (float*)d_out, nnodes, nedges);
}

// Round 5
// 114.925 us; speedup vs baseline: 1.3163x; 1.1263x over previous
//
#include <hip/hip_runtime.h>

// out[n, lm, c] = sum_{e: recv[e]==n} node_feats[send[e], c] * edge_attrs[e, lm]
//                 * tp_weights[e, L_MAP[lm], c]
// receiver_list sorted; first_occ[n] = segment start. No atomics.
// 1 wave = 1 node; lane = channel-pair (channels 2*lane, 2*lane+1): every row
// access is one 512 B/wave instruction. acc = f32x2[16] (32 VGPR).
// Main loop: 2 edges per iteration, ALL loads issued before any FMA —
// no carried deps, no in-body branch -> compiler keeps >=2 edges in flight
// (this was the regression in R3/R4: MLP, not coalescing or raw occupancy).

typedef float f32x2 __attribute__((ext_vector_type(2)));
typedef float f32x4 __attribute__((ext_vector_type(4)));

__device__ __forceinline__ void fma2(f32x2& a, const f32x2 p, const float s) {
    a.x = fmaf(p.x, s, a.x);
    a.y = fmaf(p.y, s, a.y);
}

__device__ __forceinline__ void edge_fmas(f32x2 (&acc)[16],
                                          const f32x2 sf,
                                          const f32x2 t0, const f32x2 t1,
                                          const f32x2 t2, const f32x2 t3,
                                          const f32x4 ea0, const f32x4 ea1,
                                          const f32x4 ea2, const f32x4 ea3) {
    const f32x2 p0 = sf * t0;
    const f32x2 p1 = sf * t1;
    const f32x2 p2 = sf * t2;
    const f32x2 p3 = sf * t3;
    // L_MAP = [0, 1,1,1, 2,2,2,2,2, 3,3,3,3,3,3,3]
    fma2(acc[0],  p0, ea0.x);
    fma2(acc[1],  p1, ea0.y);
    fma2(acc[2],  p1, ea0.z);
    fma2(acc[3],  p1, ea0.w);
    fma2(acc[4],  p2, ea1.x);
    fma2(acc[5],  p2, ea1.y);
    fma2(acc[6],  p2, ea1.z);
    fma2(acc[7],  p2, ea1.w);
    fma2(acc[8],  p2, ea2.x);
    fma2(acc[9],  p3, ea2.y);
    fma2(acc[10], p3, ea2.z);
    fma2(acc[11], p3, ea2.w);
    fma2(acc[12], p3, ea3.x);
    fma2(acc[13], p3, ea3.y);
    fma2(acc[14], p3, ea3.z);
    fma2(acc[15], p3, ea3.w);
}

__global__ __launch_bounds__(256)
void impt_kernel(const float* __restrict__ node_feats,
                 const float* __restrict__ edge_attrs,
                 const float* __restrict__ tp_weights,
                 const int*   __restrict__ sender_list,
                 const int*   __restrict__ first_occ,
                 float*       __restrict__ out,
                 int nnodes, int nedges)
{
    const int tid  = threadIdx.x;
    const int wv   = tid >> 6;                  // wave in block
    const int lane = tid & 63;                  // channel-pair index
    const int n    = blockIdx.x * 4 + wv;       // 4 nodes per block
    if (n >= nnodes) return;

    const int start = first_occ[n];
    const int end   = (n + 1 < nnodes) ? first_occ[n + 1] : nedges;

    f32x2 acc[16];
#pragma unroll
    for (int i = 0; i < 16; ++i) acc[i] = (f32x2)0.f;

    const float* nf = node_feats + 2 * lane;
    const float* tw = tp_weights + 2 * lane;

    int e = start;
    // -------- 2-edge unrolled main loop: all loads first, then FMAs --------
    for (; e + 2 <= end; e += 2) {
        const int sA = sender_list[e];
        const int sB = sender_list[e + 1];
        const f32x2 sfA = *reinterpret_cast<const f32x2*>(nf + (size_t)sA * 128);
        const f32x2 sfB = *reinterpret_cast<const f32x2*>(nf + (size_t)sB * 128);

        const f32x2* twA = reinterpret_cast<const f32x2*>(tw + (size_t)e * 512);
        const f32x2* twB = reinterpret_cast<const f32x2*>(tw + (size_t)(e + 1) * 512);
        const f32x2 tA0 = twA[0],   tA1 = twA[64],  tA2 = twA[128], tA3 = twA[192];
        const f32x2 tB0 = twB[0],   tB1 = twB[64],  tB2 = twB[128], tB3 = twB[192];

        const f32x4* eaA = reinterpret_cast<const f32x4*>(edge_attrs + (size_t)e * 16);
        const f32x4* eaB = reinterpret_cast<const f32x4*>(edge_attrs + (size_t)(e + 1) * 16);
        const f32x4 a0 = eaA[0], a1 = eaA[1], a2 = eaA[2], a3 = eaA[3];
        const f32x4 b0 = eaB[0], b1 = eaB[1], b2 = eaB[2], b3 = eaB[3];

        edge_fmas(acc, sfA, tA0, tA1, tA2, tA3, a0, a1, a2, a3);
        edge_fmas(acc, sfB, tB0, tB1, tB2, tB3, b0, b1, b2, b3);
    }
    // -------- tail (at most one edge) --------
    if (e < end) {
        const int s = sender_list[e];
        const f32x2 sf = *reinterpret_cast<const f32x2*>(nf + (size_t)s * 128);
        const f32x2* twp = reinterpret_cast<const f32x2*>(tw + (size_t)e * 512);
        const f32x2 t0 = twp[0], t1 = twp[64], t2 = twp[128], t3 = twp[192];
        const f32x4* ea4 = reinterpret_cast<const f32x4*>(edge_attrs + (size_t)e * 16);
        edge_fmas(acc, sf, t0, t1, t2, t3, ea4[0], ea4[1], ea4[2], ea4[3]);
    }

    // 16 coalesced 512 B/wave stores (zeros if node has no edges)
    float* o = out + (size_t)n * 2048 + 2 * lane;
#pragma unroll
    for (int lm = 0; lm < 16; ++lm) {
        *reinterpret_cast<f32x2*>(o + (size_t)lm * 128) = acc[lm];
    }
}

extern "C" void kernel_launch(void* const* d_in, const int* in_sizes, int n_in,
                              void* d_out, int out_size, void* d_ws, size_t ws_size,
                              hipStream_t stream)
{
    const float* node_feats  = (const float*)d_in[0];
    const float* edge_attrs  = (const float*)d_in[1];
    const float* tp_weights  = (const float*)d_in[2];
    const int*   sender_list = (const int*)d_in[3];
    // d_in[4] = receiver_list (unused; first_occurences encodes the segments)
    const int*   first_occ   = (const int*)d_in[5];

    const int nnodes = in_sizes[5];          // 10000
    const int nedges = in_sizes[3];          // 160000

    const int nblocks = (nnodes + 3) / 4;    // 4 nodes (waves) per block
    impt_kernel<<<nblocks, 256, 0, stream>>>(node_feats, edge_attrs, tp_weights,
                                             sender_list, first_occ,
                                             (float*)d_out, nnodes, nedges);
}

// Round 6
// 93.539 us; speedup vs baseline: 1.6172x; 1.2286x over previous
//
#include <hip/hip_runtime.h>

// out[n, lm, c] = sum_{e: recv[e]==n} node_feats[send[e], c] * edge_attrs[e, lm]
//                 * tp_weights[e, L_MAP[lm], c]
// receiver_list sorted; first_occ[n] = segment start. No atomics.
// R1 structure (best so far: 97.4 us): one 128-thread block per node,
// thread = channel, scalar dword loads (fully coalesced 256 B/wave), 16 scalar
// accumulators, ~50 VGPR -> near-max occupancy (TLP is what hides the
// index->gather->stream latency chain).
// R6 delta: depth-2 loads-first unroll — issue BOTH edges' loads (indices,
// gathers, tp rows, edge_attrs) before any FMA. Doubles per-wave MLP at
// modest VGPR cost. (R3/R4 lesson: do NOT trade occupancy for width.)

typedef float f32x4 __attribute__((ext_vector_type(4)));

__device__ __forceinline__ void edge_fmas(float (&acc)[16], const float sf,
                                          const float t0, const float t1,
                                          const float t2, const float t3,
                                          const f32x4 ea0, const f32x4 ea1,
                                          const f32x4 ea2, const f32x4 ea3) {
    const float p0 = sf * t0;
    const float p1 = sf * t1;
    const float p2 = sf * t2;
    const float p3 = sf * t3;
    // L_MAP = [0, 1,1,1, 2,2,2,2,2, 3,3,3,3,3,3,3]
    acc[0]  = fmaf(p0, ea0.x, acc[0]);
    acc[1]  = fmaf(p1, ea0.y, acc[1]);
    acc[2]  = fmaf(p1, ea0.z, acc[2]);
    acc[3]  = fmaf(p1, ea0.w, acc[3]);
    acc[4]  = fmaf(p2, ea1.x, acc[4]);
    acc[5]  = fmaf(p2, ea1.y, acc[5]);
    acc[6]  = fmaf(p2, ea1.z, acc[6]);
    acc[7]  = fmaf(p2, ea1.w, acc[7]);
    acc[8]  = fmaf(p2, ea2.x, acc[8]);
    acc[9]  = fmaf(p3, ea2.y, acc[9]);
    acc[10] = fmaf(p3, ea2.z, acc[10]);
    acc[11] = fmaf(p3, ea2.w, acc[11]);
    acc[12] = fmaf(p3, ea3.x, acc[12]);
    acc[13] = fmaf(p3, ea3.y, acc[13]);
    acc[14] = fmaf(p3, ea3.z, acc[14]);
    acc[15] = fmaf(p3, ea3.w, acc[15]);
}

__global__ __launch_bounds__(128)
void impt_kernel(const float* __restrict__ node_feats,
                 const float* __restrict__ edge_attrs,
                 const float* __restrict__ tp_weights,
                 const int*   __restrict__ sender_list,
                 const int*   __restrict__ first_occ,
                 float*       __restrict__ out,
                 int nnodes, int nedges)
{
    const int n = blockIdx.x;
    const int c = threadIdx.x;                 // 0..127 = channel
    const int start = first_occ[n];
    const int end   = (n + 1 < nnodes) ? first_occ[n + 1] : nedges;

    float acc[16];
#pragma unroll
    for (int i = 0; i < 16; ++i) acc[i] = 0.0f;

    const float* nf = node_feats + c;
    const float* tw = tp_weights + c;

    int e = start;
    // ---- depth-2 main loop: ALL loads for both edges issue before any FMA ----
    for (; e + 2 <= end; e += 2) {
        const int sA = sender_list[e];
        const int sB = sender_list[e + 1];
        const float sfA = nf[(size_t)sA * 128];
        const float sfB = nf[(size_t)sB * 128];

        const float* twA = tw + (size_t)e * 512;
        const float* twB = twA + 512;
        const float tA0 = twA[0], tA1 = twA[128], tA2 = twA[256], tA3 = twA[384];
        const float tB0 = twB[0], tB1 = twB[128], tB2 = twB[256], tB3 = twB[384];

        const f32x4* ea = reinterpret_cast<const f32x4*>(edge_attrs + (size_t)e * 16);
        const f32x4 a0 = ea[0], a1 = ea[1], a2 = ea[2], a3 = ea[3];
        const f32x4 b0 = ea[4], b1 = ea[5], b2 = ea[6], b3 = ea[7];

        edge_fmas(acc, sfA, tA0, tA1, tA2, tA3, a0, a1, a2, a3);
        edge_fmas(acc, sfB, tB0, tB1, tB2, tB3, b0, b1, b2, b3);
    }
    // ---- tail: at most one edge ----
    if (e < end) {
        const int s = sender_list[e];
        const float sf = nf[(size_t)s * 128];
        const float* twp = tw + (size_t)e * 512;
        const float t0 = twp[0], t1 = twp[128], t2 = twp[256], t3 = twp[384];
        const f32x4* ea = reinterpret_cast<const f32x4*>(edge_attrs + (size_t)e * 16);
        edge_fmas(acc, sf, t0, t1, t2, t3, ea[0], ea[1], ea[2], ea[3]);
    }

    float* o = out + (size_t)n * 2048 + c;
#pragma unroll
    for (int lm = 0; lm < 16; ++lm) o[lm * 128] = acc[lm];   // coalesced; zeros if no edges
}

extern "C" void kernel_launch(void* const* d_in, const int* in_sizes, int n_in,
                              void* d_out, int out_size, void* d_ws, size_t ws_size,
                              hipStream_t stream)
{
    const float* node_feats  = (const float*)d_in[0];
    const float* edge_attrs  = (const float*)d_in[1];
    const float* tp_weights  = (const float*)d_in[2];
    const int*   sender_list = (const int*)d_in[3];
    // d_in[4] = receiver_list (unused; first_occurences encodes the segments)
    const int*   first_occ   = (const int*)d_in[5];

    const int nnodes = in_sizes[5];          // 10000
    const int nedges = in_sizes[3];          // 160000

    impt_kernel<<<nnodes, 128, 0, stream>>>(node_feats, edge_attrs, tp_weights,
                                            sender_list, first_occ,
                                            (float*)d_out, nnodes, nedges);
}

// Round 7
// 80.617 us; speedup vs baseline: 1.8764x; 1.1603x over previous
//
#include <hip/hip_runtime.h>

// out[n, lm, c] = sum_{e: recv[e]==n} node_feats[send[e], c] * edge_attrs[e, lm]
//                 * tp_weights[e, L_MAP[lm], c]
// receiver_list sorted; first_occ[n] = segment start. No atomics.
// R6 structure (93.5 us): one 128-thread block per node, thread = channel,
// scalar dword loads (256 B/wave coalesced), depth-2 loads-first unroll,
// ~80 VGPR -> high occupancy.
// R7 delta (single lever): NON-TEMPORAL hints on all stream-once traffic
// (tp_weights, edge_attrs loads; out stores) so the reused node_feats (5.1 MB,
// gathered 160k times) stays resident in each XCD's 4 MiB L2 instead of being
// evicted by the 328 MB tp_weights stream.

typedef float f32x4 __attribute__((ext_vector_type(4)));

__device__ __forceinline__ void edge_fmas(float (&acc)[16], const float sf,
                                          const float t0, const float t1,
                                          const float t2, const float t3,
                                          const f32x4 ea0, const f32x4 ea1,
                                          const f32x4 ea2, const f32x4 ea3) {
    const float p0 = sf * t0;
    const float p1 = sf * t1;
    const float p2 = sf * t2;
    const float p3 = sf * t3;
    // L_MAP = [0, 1,1,1, 2,2,2,2,2, 3,3,3,3,3,3,3]
    acc[0]  = fmaf(p0, ea0.x, acc[0]);
    acc[1]  = fmaf(p1, ea0.y, acc[1]);
    acc[2]  = fmaf(p1, ea0.z, acc[2]);
    acc[3]  = fmaf(p1, ea0.w, acc[3]);
    acc[4]  = fmaf(p2, ea1.x, acc[4]);
    acc[5]  = fmaf(p2, ea1.y, acc[5]);
    acc[6]  = fmaf(p2, ea1.z, acc[6]);
    acc[7]  = fmaf(p2, ea1.w, acc[7]);
    acc[8]  = fmaf(p2, ea2.x, acc[8]);
    acc[9]  = fmaf(p3, ea2.y, acc[9]);
    acc[10] = fmaf(p3, ea2.z, acc[10]);
    acc[11] = fmaf(p3, ea2.w, acc[11]);
    acc[12] = fmaf(p3, ea3.x, acc[12]);
    acc[13] = fmaf(p3, ea3.y, acc[13]);
    acc[14] = fmaf(p3, ea3.z, acc[14]);
    acc[15] = fmaf(p3, ea3.w, acc[15]);
}

__global__ __launch_bounds__(128)
void impt_kernel(const float* __restrict__ node_feats,
                 const float* __restrict__ edge_attrs,
                 const float* __restrict__ tp_weights,
                 const int*   __restrict__ sender_list,
                 const int*   __restrict__ first_occ,
                 float*       __restrict__ out,
                 int nnodes, int nedges)
{
    const int n = blockIdx.x;
    const int c = threadIdx.x;                 // 0..127 = channel
    const int start = first_occ[n];
    const int end   = (n + 1 < nnodes) ? first_occ[n + 1] : nedges;

    float acc[16];
#pragma unroll
    for (int i = 0; i < 16; ++i) acc[i] = 0.0f;

    const float* nf = node_feats + c;
    const float* tw = tp_weights + c;

    int e = start;
    // ---- depth-2 main loop: ALL loads for both edges issue before any FMA ----
    for (; e + 2 <= end; e += 2) {
        const int sA = sender_list[e];
        const int sB = sender_list[e + 1];
        const float sfA = nf[(size_t)sA * 128];        // reused data: normal (cached) loads
        const float sfB = nf[(size_t)sB * 128];

        const float* twA = tw + (size_t)e * 512;
        const float* twB = twA + 512;
        const float tA0 = __builtin_nontemporal_load(twA);
        const float tA1 = __builtin_nontemporal_load(twA + 128);
        const float tA2 = __builtin_nontemporal_load(twA + 256);
        const float tA3 = __builtin_nontemporal_load(twA + 384);
        const float tB0 = __builtin_nontemporal_load(twB);
        const float tB1 = __builtin_nontemporal_load(twB + 128);
        const float tB2 = __builtin_nontemporal_load(twB + 256);
        const float tB3 = __builtin_nontemporal_load(twB + 384);

        const f32x4* ea = reinterpret_cast<const f32x4*>(edge_attrs + (size_t)e * 16);
        const f32x4 a0 = __builtin_nontemporal_load(ea);
        const f32x4 a1 = __builtin_nontemporal_load(ea + 1);
        const f32x4 a2 = __builtin_nontemporal_load(ea + 2);
        const f32x4 a3 = __builtin_nontemporal_load(ea + 3);
        const f32x4 b0 = __builtin_nontemporal_load(ea + 4);
        const f32x4 b1 = __builtin_nontemporal_load(ea + 5);
        const f32x4 b2 = __builtin_nontemporal_load(ea + 6);
        const f32x4 b3 = __builtin_nontemporal_load(ea + 7);

        edge_fmas(acc, sfA, tA0, tA1, tA2, tA3, a0, a1, a2, a3);
        edge_fmas(acc, sfB, tB0, tB1, tB2, tB3, b0, b1, b2, b3);
    }
    // ---- tail: at most one edge ----
    if (e < end) {
        const int s = sender_list[e];
        const float sf = nf[(size_t)s * 128];
        const float* twp = tw + (size_t)e * 512;
        const float t0 = __builtin_nontemporal_load(twp);
        const float t1 = __builtin_nontemporal_load(twp + 128);
        const float t2 = __builtin_nontemporal_load(twp + 256);
        const float t3 = __builtin_nontemporal_load(twp + 384);
        const f32x4* ea = reinterpret_cast<const f32x4*>(edge_attrs + (size_t)e * 16);
        const f32x4 a0 = __builtin_nontemporal_load(ea);
        const f32x4 a1 = __builtin_nontemporal_load(ea + 1);
        const f32x4 a2 = __builtin_nontemporal_load(ea + 2);
        const f32x4 a3 = __builtin_nontemporal_load(ea + 3);
        edge_fmas(acc, sf, t0, t1, t2, t3, a0, a1, a2, a3);
    }

    // coalesced stores, never re-read -> non-temporal (zeros if no edges)
    float* o = out + (size_t)n * 2048 + c;
#pragma unroll
    for (int lm = 0; lm < 16; ++lm) {
        __builtin_nontemporal_store(acc[lm], o + (size_t)lm * 128);
    }
}

extern "C" void kernel_launch(void* const* d_in, const int* in_sizes, int n_in,
                              void* d_out, int out_size, void* d_ws, size_t ws_size,
                              hipStream_t stream)
{
    const float* node_feats  = (const float*)d_in[0];
    const float* edge_attrs  = (const float*)d_in[1];
    const float* tp_weights  = (const float*)d_in[2];
    const int*   sender_list = (const int*)d_in[3];
    // d_in[4] = receiver_list (unused; first_occurences encodes the segments)
    const int*   first_occ   = (const int*)d_in[5];

    const int nnodes = in_sizes[5];          // 10000
    const int nedges = in_sizes[3];          // 160000

    impt_kernel<<<nnodes, 128, 0, stream>>>(node_feats, edge_attrs, tp_weights,
                                            sender_list, first_occ,
                                            (float*)d_out, nnodes, nedges);
}

// Round 8
// 78.891 us; speedup vs baseline: 1.9175x; 1.0219x over previous
//
#include <hip/hip_runtime.h>

// out[n, lm, c] = sum_{e: recv[e]==n} node_feats[send[e], c] * edge_attrs[e, lm]
//                 * tp_weights[e, L_MAP[lm], c]
// receiver_list sorted; first_occ[n] = segment start. No atomics.
// Structure (R7, 80.6 us): one 128-thread block per node, thread = channel,
// scalar dword loads (256 B/wave coalesced), NT on stream-once traffic.
// R8 deltas: (1) depth-4 loads-first unroll (more bytes outstanding per wait,
// half the waits); (2) edge_attrs back to CACHED loads (read by both waves of
// the block + uniform-address -> let L2/SMEM serve it; NT was hurting reuse).

typedef float f32x4 __attribute__((ext_vector_type(4)));

__device__ __forceinline__ void edge_fmas(float (&acc)[16], const float sf,
                                          const float t0, const float t1,
                                          const float t2, const float t3,
                                          const f32x4 ea0, const f32x4 ea1,
                                          const f32x4 ea2, const f32x4 ea3) {
    const float p0 = sf * t0;
    const float p1 = sf * t1;
    const float p2 = sf * t2;
    const float p3 = sf * t3;
    // L_MAP = [0, 1,1,1, 2,2,2,2,2, 3,3,3,3,3,3,3]
    acc[0]  = fmaf(p0, ea0.x, acc[0]);
    acc[1]  = fmaf(p1, ea0.y, acc[1]);
    acc[2]  = fmaf(p1, ea0.z, acc[2]);
    acc[3]  = fmaf(p1, ea0.w, acc[3]);
    acc[4]  = fmaf(p2, ea1.x, acc[4]);
    acc[5]  = fmaf(p2, ea1.y, acc[5]);
    acc[6]  = fmaf(p2, ea1.z, acc[6]);
    acc[7]  = fmaf(p2, ea1.w, acc[7]);
    acc[8]  = fmaf(p2, ea2.x, acc[8]);
    acc[9]  = fmaf(p3, ea2.y, acc[9]);
    acc[10] = fmaf(p3, ea2.z, acc[10]);
    acc[11] = fmaf(p3, ea2.w, acc[11]);
    acc[12] = fmaf(p3, ea3.x, acc[12]);
    acc[13] = fmaf(p3, ea3.y, acc[13]);
    acc[14] = fmaf(p3, ea3.z, acc[14]);
    acc[15] = fmaf(p3, ea3.w, acc[15]);
}

__global__ __launch_bounds__(128)
void impt_kernel(const float* __restrict__ node_feats,
                 const float* __restrict__ edge_attrs,
                 const float* __restrict__ tp_weights,
                 const int*   __restrict__ sender_list,
                 const int*   __restrict__ first_occ,
                 float*       __restrict__ out,
                 int nnodes, int nedges)
{
    const int n = blockIdx.x;
    const int c = threadIdx.x;                 // 0..127 = channel
    const int start = first_occ[n];
    const int end   = (n + 1 < nnodes) ? first_occ[n + 1] : nedges;

    float acc[16];
#pragma unroll
    for (int i = 0; i < 16; ++i) acc[i] = 0.0f;

    const float* nf = node_feats + c;
    const float* tw = tp_weights + c;

    int e = start;
    // ---- depth-4 main loop: ALL loads for 4 edges issue before any FMA ----
    for (; e + 4 <= end; e += 4) {
        const int s0 = sender_list[e];
        const int s1 = sender_list[e + 1];
        const int s2 = sender_list[e + 2];
        const int s3 = sender_list[e + 3];
        const float sf0 = nf[(size_t)s0 * 128];      // reused data: cached
        const float sf1 = nf[(size_t)s1 * 128];
        const float sf2 = nf[(size_t)s2 * 128];
        const float sf3 = nf[(size_t)s3 * 128];

        const float* tw0 = tw + (size_t)e * 512;
        const float* tw1 = tw0 + 512;
        const float* tw2 = tw0 + 1024;
        const float* tw3 = tw0 + 1536;
        const float tA0 = __builtin_nontemporal_load(tw0);
        const float tA1 = __builtin_nontemporal_load(tw0 + 128);
        const float tA2 = __builtin_nontemporal_load(tw0 + 256);
        const float tA3 = __builtin_nontemporal_load(tw0 + 384);
        const float tB0 = __builtin_nontemporal_load(tw1);
        const float tB1 = __builtin_nontemporal_load(tw1 + 128);
        const float tB2 = __builtin_nontemporal_load(tw1 + 256);
        const float tB3 = __builtin_nontemporal_load(tw1 + 384);
        const float tC0 = __builtin_nontemporal_load(tw2);
        const float tC1 = __builtin_nontemporal_load(tw2 + 128);
        const float tC2 = __builtin_nontemporal_load(tw2 + 256);
        const float tC3 = __builtin_nontemporal_load(tw2 + 384);
        const float tD0 = __builtin_nontemporal_load(tw3);
        const float tD1 = __builtin_nontemporal_load(tw3 + 128);
        const float tD2 = __builtin_nontemporal_load(tw3 + 256);
        const float tD3 = __builtin_nontemporal_load(tw3 + 384);

        const f32x4* ea = reinterpret_cast<const f32x4*>(edge_attrs + (size_t)e * 16);
        const f32x4 a0 = ea[0],  a1 = ea[1],  a2 = ea[2],  a3 = ea[3];
        const f32x4 b0 = ea[4],  b1 = ea[5],  b2 = ea[6],  b3 = ea[7];
        const f32x4 c0 = ea[8],  c1 = ea[9],  c2 = ea[10], c3 = ea[11];
        const f32x4 d0 = ea[12], d1 = ea[13], d2 = ea[14], d3 = ea[15];

        edge_fmas(acc, sf0, tA0, tA1, tA2, tA3, a0, a1, a2, a3);
        edge_fmas(acc, sf1, tB0, tB1, tB2, tB3, b0, b1, b2, b3);
        edge_fmas(acc, sf2, tC0, tC1, tC2, tC3, c0, c1, c2, c3);
        edge_fmas(acc, sf3, tD0, tD1, tD2, tD3, d0, d1, d2, d3);
    }
    // ---- tail: up to 3 single edges ----
    for (; e < end; ++e) {
        const int s = sender_list[e];
        const float sf = nf[(size_t)s * 128];
        const float* twp = tw + (size_t)e * 512;
        const float t0 = __builtin_nontemporal_load(twp);
        const float t1 = __builtin_nontemporal_load(twp + 128);
        const float t2 = __builtin_nontemporal_load(twp + 256);
        const float t3 = __builtin_nontemporal_load(twp + 384);
        const f32x4* ea = reinterpret_cast<const f32x4*>(edge_attrs + (size_t)e * 16);
        edge_fmas(acc, sf, t0, t1, t2, t3, ea[0], ea[1], ea[2], ea[3]);
    }

    // coalesced stores, never re-read -> non-temporal (zeros if no edges)
    float* o = out + (size_t)n * 2048 + c;
#pragma unroll
    for (int lm = 0; lm < 16; ++lm) {
        __builtin_nontemporal_store(acc[lm], o + (size_t)lm * 128);
    }
}

extern "C" void kernel_launch(void* const* d_in, const int* in_sizes, int n_in,
                              void* d_out, int out_size, void* d_ws, size_t ws_size,
                              hipStream_t stream)
{
    const float* node_feats  = (const float*)d_in[0];
    const float* edge_attrs  = (const float*)d_in[1];
    const float* tp_weights  = (const float*)d_in[2];
    const int*   sender_list = (const int*)d_in[3];
    // d_in[4] = receiver_list (unused; first_occurences encodes the segments)
    const int*   first_occ   = (const int*)d_in[5];

    const int nnodes = in_sizes[5];          // 10000
    const int nedges = in_sizes[3];          // 160000

    impt_kernel<<<nnodes, 128, 0, stream>>>(node_feats, edge_attrs, tp_weights,
                                            sender_list, first_occ,
                                            (float*)d_out, nnodes, nedges);
}